// Round 6
// baseline (298.698 us; speedup 1.0000x reference)
//
#include <hip/hip_runtime.h>

#define BATCH 64
#define SEQ   128
#define NLAB  32
#define NEGF  -3.0e38f
// PA = 140 (row pitch, floats). 140 ≡ 12 (mod 32 banks): phase-A window
// loads (16 lanes, consecutive rows, stride 140) hit 8 distinct 4-bank
// spans -> 2-way (free). Phase-B quad streams (stride-PA rows) likewise 2-way.
#define PA    140

// counted-waitcnt barrier: wait until <=K LDS ops outstanding, then s_barrier.
// DS ops retire in-order, so writes issued BEFORE the last K reads are complete.
__device__ __forceinline__ void bar_k(int K) {
    switch (K) {
    case 0: asm volatile("s_waitcnt lgkmcnt(0)" ::: "memory"); break;
    case 1: asm volatile("s_waitcnt lgkmcnt(1)" ::: "memory"); break;
    case 2: asm volatile("s_waitcnt lgkmcnt(2)" ::: "memory"); break;
    default: asm volatile("s_waitcnt lgkmcnt(4)" ::: "memory"); break;
    }
    __builtin_amdgcn_s_barrier();
}

// cross-lane max via DPP (VALU pipe, not DS pipe)
__device__ __forceinline__ float qmax1(float v) {   // xor 1 within quad
    int t = __builtin_amdgcn_update_dpp(0, __float_as_int(v), 0xB1, 0xF, 0xF, true);
    return fmaxf(v, __int_as_float(t));
}
__device__ __forceinline__ float qmax2(float v) {   // xor 2 within quad
    int t = __builtin_amdgcn_update_dpp(0, __float_as_int(v), 0x4E, 0xF, 0xF, true);
    return fmaxf(v, __int_as_float(t));
}
__device__ __forceinline__ float rmax4(float v) {   // row_ror:4 (16-lane row)
    int t = __builtin_amdgcn_update_dpp(0, __float_as_int(v), 0x124, 0xF, 0xF, true);
    return fmaxf(v, __int_as_float(t));
}
__device__ __forceinline__ float rmax8(float v) {   // row_ror:8
    int t = __builtin_amdgcn_update_dpp(0, __float_as_int(v), 0x128, 0xF, 0xF, true);
    return fmaxf(v, __int_as_float(t));
}

// ---------------------------------------------------------------------------
// Kernel 1 (v5): pot + gold partials + inline len + out zeroing. (unchanged)
// ---------------------------------------------------------------------------
__global__ __launch_bounds__(256) void pot_gold_kernel(
    const float* __restrict__ logits, const int* __restrict__ labels,
    float* __restrict__ pot, float* __restrict__ gpart, float* __restrict__ out)
{
    const int tid = threadIdx.x;
    const int wave = tid >> 6, lane = tid & 63;
    __shared__ __align__(16) float LP[4 * 16 * 36];   // 9216 B
    __shared__ float gred[4];
    __shared__ int s_len;
    float* W = LP + wave * (16 * 36);

    const int block_cell0 = blockIdx.x * 256;
    const int b = block_cell0 >> 14;
    const bool has_row0 = (blockIdx.x & 63) == 0;

    if (blockIdx.x == 0 && tid == 0) out[0] = 0.0f;   // replaces hipMemsetAsync

    if (has_row0 && tid < 64) {
        const size_t base = (size_t)b << 14;
        int cnt = (labels[base + tid] != -100) + (labels[base + 64 + tid] != -100);
        #pragma unroll
        for (int d = 32; d; d >>= 1) cnt += __shfl_down(cnt, d, 64);
        if (tid == 0) s_len = cnt;
    }
    __syncthreads();
    const int len = has_row0 ? s_len : -1;

    float gacc = 0.0f;
    const int wave_cell0 = block_cell0 + wave * 64;

    #pragma unroll
    for (int chunk = 0; chunk < 4; ++chunk) {
        const int c0 = wave_cell0 + chunk * 16;
        const float4* src = reinterpret_cast<const float4*>(logits) + ((size_t)c0 << 3);
        const float4 f0 = src[lane];
        const float4 f1 = src[lane + 64];
        const int lv = (lane < 16) ? labels[c0 + lane] : 0;

        {
            const int cA = lane >> 3, tA = lane & 7;
            *reinterpret_cast<float4*>(W + cA * 36 + tA * 4) = f0;
            const int q1 = lane + 64;
            const int cB = q1 >> 3, tB = q1 & 7;
            *reinterpret_cast<float4*>(W + cB * 36 + tB * 4) = f1;
        }
        const int c = lane >> 2, u = lane & 3;
        const float4 r0 = *reinterpret_cast<const float4*>(W + c * 36 + u * 8);
        const float4 r1 = *reinterpret_cast<const float4*>(W + c * 36 + u * 8 + 4);

        int lab = __shfl(lv, c, 64);
        if (lab < 0) lab = 0;
        const float l0 = __shfl(r0.x, c << 2, 64);

        const int cell = c0 + c;
        const int ci = (cell >> 7) & (SEQ - 1);
        const int cj = cell & (SEQ - 1);
        const bool special = (ci == 0) && (cj == len - 1);

        const float vv[8] = { r0.x, r0.y, r0.z, r0.w, r1.x, r1.y, r1.z, r1.w };
        float m = NEGF, g = 0.0f;
        #pragma unroll
        for (int e = 0; e < 8; ++e) {
            const int l = u * 8 + e;
            const float r = vv[e] - l0;
            const bool isg = (l == lab);
            g = isg ? r : g;
            float cand = r + (isg ? 0.0f : 1.0f);
            if (l == 0 && special) cand -= 1.0e9f;
            m = fmaxf(m, cand);
        }
        m = fmaxf(m, __shfl_xor(m, 1, 64));
        m = fmaxf(m, __shfl_xor(m, 2, 64));
        g += __shfl_xor(g, 1, 64);
        g += __shfl_xor(g, 2, 64);
        if (u == 0) {
            pot[cell] = m;
            gacc += g;
        }
    }

    #pragma unroll
    for (int d = 1; d < 64; d <<= 1) gacc += __shfl_xor(gacc, d, 64);
    if (lane == 0) gred[wave] = gacc;
    __syncthreads();
    if (tid == 0)
        gpart[blockIdx.x] = gred[0] + gred[1] + gred[2] + gred[3];
}

// ---------------------------------------------------------------------------
// Kernel 2 (v12): NEGF-poisoned tables + p-sweep phase A (aligned b128 rows).
//   A[i][k]  = score of span [i,i+k], NEGF where not computed (incl. pads and
//              a 16-float guard BEFORE A for small-col reads).
//   Bulk: md[i][d] = max_{pp in [1, W+16]} A[i][pp-1-(i-i0 offset)] ... i.e.
//         for group rows i0+r: md = max A[i0+r][pp-1-r] + A[i0+pp][W+r+d-pp].
//   Poison auto-excludes: k >= W (fresh), k < d (right side >= W fresh),
//   invalid rows, OOB j. No masks needed.
//   Per 16-lane group iter: 4 b32 + 6 b128 cover 4 rows x 16 p x 16 d.
//   16-lane allreduce via DPP; one b128/lane stages md to phase-B layout.
// Phase B / chunk 0: verified v10b structure (md from stage, pv from global).
// ---------------------------------------------------------------------------
__global__ __launch_bounds__(512, 1) void cky_kernel(
    const float* __restrict__ pot, const float* __restrict__ gpart,
    const int* __restrict__ labels, float* __restrict__ out)
{
    const int b = blockIdx.x;
    const int tid = threadIdx.x;
    const float* p = pot + (size_t)b * SEQ * SEQ;

    // [guard 16][A 128*140][Bt 128*140][stage 128*20]
    __shared__ __align__(16) float SH[16 + 2 * SEQ * PA + SEQ * 20];
    float* A = SH + 16;
    float* Bt = A + SEQ * PA;
    float* stage = Bt + SEQ * PA;
    __shared__ int s_len;
    __shared__ float s_gold;

    {   // poison everything to NEGF
        const float4 nf = { NEGF, NEGF, NEGF, NEGF };
        float4* sh4 = reinterpret_cast<float4*>(SH);
        const int NQ4 = (16 + 2 * SEQ * PA + SEQ * 20) / 4;
        for (int q = tid; q < NQ4; q += 512) sh4[q] = nf;
    }
    __syncthreads();

    if (tid < 128) {                                  // diagonal (width 0)
        const float v = p[tid * 129];
        A[tid * PA] = v;
        Bt[tid * PA + (SEQ - 1)] = v;
    } else if (tid < 192) {                           // len[b]
        const int lane = tid - 128;
        const size_t base = (size_t)b << 14;
        int cnt = (labels[base + lane] != -100) + (labels[base + 64 + lane] != -100);
        #pragma unroll
        for (int d = 32; d; d >>= 1) cnt += __shfl_down(cnt, d, 64);
        if (lane == 0) s_len = cnt;
    } else if (tid < 256) {                           // gold[b]
        const int lane = tid - 192;
        float g = gpart[b * 64 + lane];
        #pragma unroll
        for (int d = 32; d; d >>= 1) g += __shfl_down(g, d, 64);
        if (lane == 0) s_gold = g;
    }
    __syncthreads();

    const int i = tid >> 2, s = tid & 3;
    float av[16], alo[16];
    float boq[4], bfq[4];

    // lane-s edge body, chunk 0 (bo terms only; fresh-quad lane uses fq)
#define C0_BODY(Sv)                                                           \
    if (s == (Sv)) {                                                          \
        _Pragma("unroll")                                                     \
        for (int e = 0; e < 4; ++e) {                                         \
            const int m = 4 * (Sv) + e;                                       \
            if (m < d) {                                                      \
                const float bv = ((Sv) == ((d - 1) >> 2))                     \
                    ? ((e == 0) ? fq.w : (e == 1) ? fq.z : (e == 2) ? fq.y : fq.x) \
                    : boq[e];                                                 \
                part = fmaxf(part, av[d - 1 - m] + bv);                       \
            }                                                                 \
        }                                                                     \
    }

    // lane-s edge body, chunks >= 16 (bo via prefetch, bf fresh-or-prefetch)
#define CH_BODY(Sv)                                                           \
    if (s == (Sv)) {                                                          \
        _Pragma("unroll")                                                     \
        for (int e = 0; e < 4; ++e) {                                         \
            const int m = 4 * (Sv) + e;                                       \
            if (m < d) {                                                      \
                part = fmaxf(part, av[d - 1 - m] + boq[e]);                   \
                const float bv = ((Sv) == ((d - 1) >> 2))                     \
                    ? ((e == 0) ? fq.w : (e == 1) ? fq.z : (e == 2) ? fq.y : fq.x) \
                    : bfq[e];                                                 \
                part = fmaxf(part, alo[d - 1 - m] + bv);                      \
            }                                                                 \
        }                                                                     \
    }

    // ---------------- chunk 0: w = 1..15 ----------------
    float pvc[16];
    {
        const float* prow = p + i * 129;
        #pragma unroll
        for (int k = 0; k < 16; ++k) pvc[k] = prow[k];
    }
    av[0] = pvc[0];

    {   // initial prefetch for step d=1 (row i+1, quad t=s, widths 4s..4s+3)
        const int jp = (i + 1 < SEQ) ? (i + 1) : (SEQ - 1);
        const float4 bv = *reinterpret_cast<const float4*>(&Bt[jp * PA + 124 - 4 * s]);
        boq[0] = bv.w; boq[1] = bv.z; boq[2] = bv.y; boq[3] = bv.x;
    }

    #pragma unroll
    for (int d = 1; d < 16; ++d) {
        const int j = i + d;
        const int jr = (j < SEQ) ? j : SEQ - 1;
        // uniform fresh quad: t = (d-1)>>2 of row j (contains width d-1)
        const float4 fq = *reinterpret_cast<const float4*>(&Bt[jr * PA + 124 - 4 * ((d - 1) >> 2)]);
        float part = NEGF;
        C0_BODY(0)
        C0_BODY(1)
        C0_BODY(2)
        C0_BODY(3)
        part = qmax2(qmax1(part));
        const float val = part + pvc[d];
        av[d] = val;
        if (j < SEQ && s < 2) {
            float* pw = (s == 0) ? &A[i * PA + d] : &Bt[j * PA + (SEQ - 1 - d)];
            *pw = val;
        }
        __builtin_amdgcn_sched_barrier(0);
        if (d < 15) {   // prefetch own quad t=s of row j+1 for step d+1
            const int jp = (j + 1 < SEQ) ? (j + 1) : (SEQ - 1);
            const float4 bv = *reinterpret_cast<const float4*>(&Bt[jp * PA + 124 - 4 * s]);
            boq[0] = bv.w; boq[1] = bv.z; boq[2] = bv.y; boq[3] = bv.x;
            bar_k(1);
        } else {
            bar_k(0);
        }
    }

    // ---------------- chunks W = 16..112 ----------------
    for (int W = 16; W < SEQ; W += 16) {
        // pv for phase B from global pot (issued early; latency hides under phase A)
        float pvn[16];
        {
            const float* prow = p + i * 129 + W;
            #pragma unroll
            for (int k = 0; k < 16; ++k) pvn[k] = prow[k];
        }

        // ---- phase A: p-sweep bulk ----
        {
            const int g16 = tid >> 4;
            const int i0a = g16 << 2;
            const int sp = tid & 15;
            if (i0a + W <= 127) {
                float md2[4][16];
                #pragma unroll
                for (int r = 0; r < 4; ++r)
                    #pragma unroll
                    for (int dd = 0; dd < 16; ++dd) md2[r][dd] = NEGF;

                const int NIT = (W >> 4) + 1;
                for (int n = 0; n < NIT; ++n) {
                    const int pp = 1 + (n << 4) + sp;       // pp in [1, W+16]
                    const int prow_ = i0a + pp;             // may exceed 127: in-LDS, auto-excluded
                    float avv[4];
                    #pragma unroll
                    for (int r = 0; r < 4; ++r)
                        avv[r] = A[(i0a + r) * PA + (pp - 1 - r)];   // guard covers col >= -3
                    const int st = W - pp;                  // may be negative (>= -16)
                    const int al = st & ~3;                 // floor to quad
                    const int rot = st & 3;
                    const float* wp = &A[prow_ * PA + al];  // >= SH (guard)
                    float w[24];
                    #pragma unroll
                    for (int t = 0; t < 6; ++t) {
                        const float4 v = *reinterpret_cast<const float4*>(wp + 4 * t);
                        w[4*t] = v.x; w[4*t+1] = v.y; w[4*t+2] = v.z; w[4*t+3] = v.w;
                    }
                    const bool r1 = (rot & 1) != 0, r2 = (rot & 2) != 0;
                    float wr[19];
                    #pragma unroll
                    for (int k = 0; k < 19; ++k) {
                        const float lo = r1 ? w[k + 1] : w[k];
                        const float hi = r1 ? w[k + 3] : w[k + 2];
                        wr[k] = r2 ? hi : lo;
                    }
                    #pragma unroll
                    for (int r = 0; r < 4; ++r)
                        #pragma unroll
                        for (int dd = 0; dd < 16; ++dd)
                            md2[r][dd] = fmaxf(md2[r][dd], avv[r] + wr[r + dd]);
                }
                // 16-lane allreduce (DPP, VALU pipe)
                #pragma unroll
                for (int r = 0; r < 4; ++r)
                    #pragma unroll
                    for (int dd = 0; dd < 16; ++dd)
                        md2[r][dd] = rmax8(rmax4(qmax2(qmax1(md2[r][dd]))));
                // stage write: lane sp emits quad (r = sp>>2, dq = sp&3)
                float o[4];
                #pragma unroll
                for (int e = 0; e < 4; ++e) {
#define DQSEL(R) ((sp & 2) ? ((sp & 1) ? md2[R][12 + e] : md2[R][8 + e])      \
                           : ((sp & 1) ? md2[R][4 + e]  : md2[R][e]))
                    const float v0 = DQSEL(0), v1 = DQSEL(1),
                                v2 = DQSEL(2), v3 = DQSEL(3);
#undef DQSEL
                    o[e] = (sp & 8) ? ((sp & 4) ? v3 : v2)
                                    : ((sp & 4) ? v1 : v0);
                }
                float4 ov; ov.x = o[0]; ov.y = o[1]; ov.z = o[2]; ov.w = o[3];
                *reinterpret_cast<float4*>(
                    &stage[(i0a + (sp >> 2)) * 20 + ((sp & 3) << 2)]) = ov;
            }
        }
        __syncthreads();

        // re-read alo (A[i][0..15], fixed after chunk 0; poison where invalid)
        #pragma unroll
        for (int t = 0; t < 4; ++t) {
            const float4 v = *reinterpret_cast<const float4*>(&A[i * PA + 4 * t]);
            alo[4*t] = v.x; alo[4*t+1] = v.y; alo[4*t+2] = v.z; alo[4*t+3] = v.w;
        }
        float mdv[16];
        #pragma unroll
        for (int t = 0; t < 4; ++t) {
            const float4 v = *reinterpret_cast<const float4*>(&stage[i * 20 + 4 * t]);
            mdv[4*t] = v.x; mdv[4*t+1] = v.y; mdv[4*t+2] = v.z; mdv[4*t+3] = v.w;
        }

        // ---- phase B (verified v10b structure) ----
        {   // step d = 0: no edge terms; prefetch both quads for step 1
            const int j = i + W;
            const float val = mdv[0] + pvn[0];
            av[0] = val;
            if (j < SEQ && s < 2) {
                float* pw = (s == 0) ? &A[i * PA + W] : &Bt[j * PA + (SEQ - 1 - W)];
                *pw = val;
            }
            __builtin_amdgcn_sched_barrier(0);
            const int jp = (j + 1 < SEQ) ? (j + 1) : (SEQ - 1);
            const float4 bv = *reinterpret_cast<const float4*>(&Bt[jp * PA + 124 - 4 * s]);
            const float4 fv = *reinterpret_cast<const float4*>(&Bt[jp * PA + 124 - W - 4 * s]);
            boq[0] = bv.w; boq[1] = bv.z; boq[2] = bv.y; boq[3] = bv.x;
            bfq[0] = fv.w; bfq[1] = fv.z; bfq[2] = fv.y; bfq[3] = fv.x;
            bar_k(2);
        }
        #pragma unroll
        for (int d = 1; d < 16; ++d) {
            const int w = W + d;
            const int j = i + w;
            const int jr = (j < SEQ) ? j : SEQ - 1;
            // uniform fresh bf quad: t=(d-1)>>2 of row j (contains width w-1)
            const float4 fq = *reinterpret_cast<const float4*>(
                &Bt[jr * PA + 124 - W - 4 * ((d - 1) >> 2)]);
            float part = NEGF;
            CH_BODY(0)
            CH_BODY(1)
            CH_BODY(2)
            CH_BODY(3)
            part = qmax2(qmax1(part));
            const float val = fmaxf(part, mdv[d]) + pvn[d];
            av[d] = val;
            if (j < SEQ && s < 2) {
                float* pw = (s == 0) ? &A[i * PA + w] : &Bt[j * PA + (SEQ - 1 - w)];
                *pw = val;
            }
            __builtin_amdgcn_sched_barrier(0);
            if (d < 15) {   // prefetch own bo+bf quads of row j+1 for step d+1
                const int jp = (j + 1 < SEQ) ? (j + 1) : (SEQ - 1);
                const float4 bv = *reinterpret_cast<const float4*>(&Bt[jp * PA + 124 - 4 * s]);
                const float4 fv = *reinterpret_cast<const float4*>(&Bt[jp * PA + 124 - W - 4 * s]);
                boq[0] = bv.w; boq[1] = bv.z; boq[2] = bv.y; boq[3] = bv.x;
                bfq[0] = fv.w; bfq[1] = fv.z; bfq[2] = fv.y; bfq[3] = fv.x;
                bar_k(2);
            } else {
                bar_k(0);
            }
        }
    }

    if (tid == 0) {
        const int len = s_len;
        const float pred = A[len - 1];        // A[0][len-1]
        const float margin = fmaxf(pred - s_gold, 0.0f);
        atomicAdd(out, margin * (1.0f / (float)BATCH));
    }
#undef C0_BODY
#undef CH_BODY
}

extern "C" void kernel_launch(void* const* d_in, const int* in_sizes, int n_in,
                              void* d_out, int out_size, void* d_ws, size_t ws_size,
                              hipStream_t stream) {
    const float* logits = (const float*)d_in[0];
    const int* labels = (const int*)d_in[1];
    float* out = (float*)d_out;

    float* pot = (float*)d_ws;                          // B*N*N floats = 4 MB
    float* gpart = pot + (size_t)BATCH * SEQ * SEQ;     // 4096 floats

    pot_gold_kernel<<<BATCH * SEQ * SEQ / 256, 256, 0, stream>>>(
        logits, labels, pot, gpart, out);
    cky_kernel<<<BATCH, 512, 0, stream>>>(pot, gpart, labels, out);
}